// Round 2
// baseline (373.255 us; speedup 1.0000x reference)
//
#include <hip/hip_runtime.h>
#include <math.h>

// Capsule routing, fused, fp32, occupancy-rebuilt.
// x: [256][1152][8]  W: [1152][10][16][8]
// out: v [256][10][16] (40960) then c_out broadcast [256][1152][10] (2949120)
//
// ws layout (floats):
//   s_part @ 0               KB*40960   (KB = 64 if ws fits, else 32)
//   b1 @ KB*40960 (11520), b2 (+11520), c2, c3, v1 (40960), v2 (40960),
//   db0 (11520), db1 (11520)  -> total KB*40960 + 151040 floats

// ---------------------------------------------------------------------------
// k_s: s_part[kb][b][n] = sum_{k in slab} x[b][k] * (c[r(k),c(n)] * W[k][n])
// GEMM M=256 N=160 K=9216, split-K. grid = bt(16, M-tile 16) x kb(KB).
// block 128 = tng(32, TN=5) x tmg(4, TM=4). Chunks of 3 routes (24 kk).
__global__ __launch_bounds__(128) void k_s(const float* __restrict__ x,
                                           const float* __restrict__ W,
                                           const float* __restrict__ cw, // [1152][10] or null -> 1/1152
                                           float* __restrict__ s_part,
                                           int KB)
{
    __shared__ float Ws[24 * 160];   // [kk][n]
    __shared__ float Xs[24 * 16];    // [kk][m]
    __shared__ float cwl[368];       // slab's c_ij (Rslab*10 <= 360)

    const int kb = blockIdx.x % KB;
    const int bt = blockIdx.x / KB;
    const int Rslab = 1152 / KB;      // 18 (KB=64) or 36 (KB=32)
    const int nch = Rslab / 3;        // chunks of 3 routes
    const int r_base = kb * Rslab;
    const int b0 = bt * 16;
    const int tid = threadIdx.x;
    const int tng = tid & 31;         // n = tng*5
    const int tmg = tid >> 5;         // m = tmg*4

    const float4* __restrict__ W4 = reinterpret_cast<const float4*>(W);
    const float4* __restrict__ X4 = reinterpret_cast<const float4*>(x);

    const float inv1152 = 1.0f / 1152.0f;
    for (int t = tid; t < Rslab * 10; t += 128)
        cwl[t] = cw ? cw[r_base * 10 + t] : inv1152;

    float acc[4][5];
#pragma unroll
    for (int a = 0; a < 4; ++a)
#pragma unroll
        for (int j = 0; j < 5; ++j) acc[a][j] = 0.f;

    // chunk staging registers (prefetched)
    float4 wreg[8];
    float4 xreg;
    const int xmi = tid / 6;          // 0..21 (valid < 96)
    const int xkq = tid % 6;

    // ---- issue global loads for chunk ch into registers ----
    auto load_chunk = [&](int ch) {
        const int r0g = r_base + ch * 3;
#pragma unroll
        for (int q = 0; q < 8; ++q) {
            const int idx = q * 128 + tid;
            if (idx < 960) {
                const int rl = idx / 320, rem = idx % 320;
                wreg[q] = W4[(r0g + rl) * 320 + rem];
            }
        }
        if (tid < 96)
            xreg = X4[(b0 + xmi) * 2304 + r0g * 2 + xkq];
    };
    // ---- scale + write chunk ch registers into LDS ----
    auto write_chunk = [&](int ch) {
#pragma unroll
        for (int q = 0; q < 8; ++q) {
            const int idx = q * 128 + tid;
            if (idx < 960) {
                const int rl = idx / 320, rem = idx % 320;
                const int h = rem & 1, o = (rem >> 1) & 15, cc = rem >> 5;
                const float sc = cwl[(ch * 3 + rl) * 10 + cc];
                const int kk = rl * 8 + h * 4;
                const int n = cc * 16 + o;
                Ws[(kk + 0) * 160 + n] = wreg[q].x * sc;
                Ws[(kk + 1) * 160 + n] = wreg[q].y * sc;
                Ws[(kk + 2) * 160 + n] = wreg[q].z * sc;
                Ws[(kk + 3) * 160 + n] = wreg[q].w * sc;
            }
        }
        if (tid < 96) {
            Xs[(xkq * 4 + 0) * 16 + xmi] = xreg.x;
            Xs[(xkq * 4 + 1) * 16 + xmi] = xreg.y;
            Xs[(xkq * 4 + 2) * 16 + xmi] = xreg.z;
            Xs[(xkq * 4 + 3) * 16 + xmi] = xreg.w;
        }
    };

    load_chunk(0);
    for (int ch = 0; ch < nch; ++ch) {
        __syncthreads();              // prev compute done (and cwl ready)
        write_chunk(ch);
        __syncthreads();
        if (ch + 1 < nch) load_chunk(ch + 1);   // overlap with compute
#pragma unroll 6
        for (int kk = 0; kk < 24; ++kk) {
            const float4 xv = *reinterpret_cast<const float4*>(&Xs[kk * 16 + tmg * 4]);
            const float* wr = &Ws[kk * 160 + tng * 5];
            const float w0 = wr[0], w1 = wr[1], w2 = wr[2], w3 = wr[3], w4 = wr[4];
            acc[0][0] = fmaf(xv.x, w0, acc[0][0]);
            acc[0][1] = fmaf(xv.x, w1, acc[0][1]);
            acc[0][2] = fmaf(xv.x, w2, acc[0][2]);
            acc[0][3] = fmaf(xv.x, w3, acc[0][3]);
            acc[0][4] = fmaf(xv.x, w4, acc[0][4]);
            acc[1][0] = fmaf(xv.y, w0, acc[1][0]);
            acc[1][1] = fmaf(xv.y, w1, acc[1][1]);
            acc[1][2] = fmaf(xv.y, w2, acc[1][2]);
            acc[1][3] = fmaf(xv.y, w3, acc[1][3]);
            acc[1][4] = fmaf(xv.y, w4, acc[1][4]);
            acc[2][0] = fmaf(xv.z, w0, acc[2][0]);
            acc[2][1] = fmaf(xv.z, w1, acc[2][1]);
            acc[2][2] = fmaf(xv.z, w2, acc[2][2]);
            acc[2][3] = fmaf(xv.z, w3, acc[2][3]);
            acc[2][4] = fmaf(xv.z, w4, acc[2][4]);
            acc[3][0] = fmaf(xv.w, w0, acc[3][0]);
            acc[3][1] = fmaf(xv.w, w1, acc[3][1]);
            acc[3][2] = fmaf(xv.w, w2, acc[3][2]);
            acc[3][3] = fmaf(xv.w, w3, acc[3][3]);
            acc[3][4] = fmaf(xv.w, w4, acc[3][4]);
        }
    }

#pragma unroll
    for (int mi = 0; mi < 4; ++mi) {
        float* dst = &s_part[(size_t)(kb * 256 + b0 + tmg * 4 + mi) * 160 + tng * 5];
#pragma unroll
        for (int j = 0; j < 5; ++j) dst[j] = acc[mi][j];
    }
}

// ---------------------------------------------------------------------------
// k_v: v[b][c][o] = squash( sum_kb s_part[kb][b][c*16+o] )
__global__ __launch_bounds__(256) void k_v(const float* __restrict__ s_part,
                                           float* __restrict__ v, int KB)
{
    const int bgrp = blockIdx.x / 5;
    const int cp   = blockIdx.x % 5;
    const int b = bgrp * 16 + (threadIdx.x >> 4);
    const int o = threadIdx.x & 15;
    for (int cc = 0; cc < 2; ++cc) {
        const int c = cp * 2 + cc;
        float s = 0.f;
        const float* p = &s_part[b * 160 + c * 16 + o];
        for (int kbv = 0; kbv < KB; ++kbv) s += p[(size_t)kbv * 40960];
        float sq = s * s;
#pragma unroll
        for (int off = 1; off < 16; off <<= 1) sq += __shfl_xor(sq, off, 16);
        const float scale = (sq / (1.f + sq)) / sqrtf(sq + 1e-9f);
        v[b * 160 + c * 16 + o] = s * scale;
    }
}

// ---------------------------------------------------------------------------
// k_a: db[r][c] = sum_b sum_o u_hat[b,r,c,o] * v[b,c,o]  (/256 applied in k_sm)
// T-GEMM: T[m=(r,i)][n=(c,o)] = sum_b x[b][m] v[b][n]; M=9216 N=160 K=256.
// grid 576 (M-tile 16 = 2 routes, no K-split -> db written directly, no atomics
// on global). block 128 = tng(32,TN=5) x tmg(4,TM=4). Inner vectorized over b.
__global__ __launch_bounds__(128) void k_a(const float* __restrict__ x,
                                           const float* __restrict__ v,
                                           const float* __restrict__ W,
                                           float* __restrict__ db)
{
    __shared__ float Vst[160 * 36];  // [n][b] padded
    __shared__ float Xn[16 * 36];    // [m][b] padded
    __shared__ float dbl[20];
    const int m0 = blockIdx.x * 16;
    const int r0 = m0 >> 3;
    const int tid = threadIdx.x;
    const int tng = tid & 31;
    const int tmg = tid >> 5;
    if (tid < 20) dbl[tid] = 0.f;

    const float4* __restrict__ V4 = reinterpret_cast<const float4*>(v);
    const float4* __restrict__ X4 = reinterpret_cast<const float4*>(x);

    float acc[4][5];
#pragma unroll
    for (int a = 0; a < 4; ++a)
#pragma unroll
        for (int j = 0; j < 5; ++j) acc[a][j] = 0.f;

    const int xbb = tid >> 2, xq = tid & 3;

    for (int bc = 0; bc < 8; ++bc) {
        const int b0 = bc * 32;
        __syncthreads();
        // stage V^T chunk [160][32]
        for (int idx = tid; idx < 1280; idx += 128) {
            const int bb = idx / 40, nq = idx % 40;
            const float4 v4 = V4[(b0 + bb) * 40 + nq];
            Vst[(nq * 4 + 0) * 36 + bb] = v4.x;
            Vst[(nq * 4 + 1) * 36 + bb] = v4.y;
            Vst[(nq * 4 + 2) * 36 + bb] = v4.z;
            Vst[(nq * 4 + 3) * 36 + bb] = v4.w;
        }
        // stage x^T chunk [16][32]
        {
            const float4 x4 = X4[(b0 + xbb) * 2304 + (m0 >> 2) + xq];
            Xn[(xq * 4 + 0) * 36 + xbb] = x4.x;
            Xn[(xq * 4 + 1) * 36 + xbb] = x4.y;
            Xn[(xq * 4 + 2) * 36 + xbb] = x4.z;
            Xn[(xq * 4 + 3) * 36 + xbb] = x4.w;
        }
        __syncthreads();
#pragma unroll
        for (int s4 = 0; s4 < 8; ++s4) {
            float4 xv[4];
#pragma unroll
            for (int mi = 0; mi < 4; ++mi)
                xv[mi] = *reinterpret_cast<const float4*>(&Xn[(tmg * 4 + mi) * 36 + s4 * 4]);
#pragma unroll
            for (int j = 0; j < 5; ++j) {
                const float4 vj = *reinterpret_cast<const float4*>(&Vst[(tng * 5 + j) * 36 + s4 * 4]);
#pragma unroll
                for (int mi = 0; mi < 4; ++mi) {
                    acc[mi][j] = fmaf(xv[mi].x, vj.x, acc[mi][j]);
                    acc[mi][j] = fmaf(xv[mi].y, vj.y, acc[mi][j]);
                    acc[mi][j] = fmaf(xv[mi].z, vj.z, acc[mi][j]);
                    acc[mi][j] = fmaf(xv[mi].w, vj.w, acc[mi][j]);
                }
            }
        }
    }

    // epilogue: contract T-tile with W -> db partials for this block's 2 routes
    const int rl = tmg >> 1;   // tmg 0,1 -> route 0; 2,3 -> route 1
    const int c0 = (tng * 5) >> 4;
    const int c1 = (tng * 5 + 4) >> 4;
    float p0 = 0.f, p1 = 0.f;
#pragma unroll
    for (int mi = 0; mi < 4; ++mi) {
        const int ml = tmg * 4 + mi;
        const int i = ml & 7;
        const int r = r0 + rl;
#pragma unroll
        for (int j = 0; j < 5; ++j) {
            const int n = tng * 5 + j;
            const int c = n >> 4, o = n & 15;
            const float w = W[(((r * 10 + c) * 16 + o) * 8) + i];
            const float t = w * acc[mi][j];
            if (c == c0) p0 += t; else p1 += t;
        }
    }
    __syncthreads();
    atomicAdd(&dbl[rl * 10 + c0], p0);
    if (c1 != c0) atomicAdd(&dbl[rl * 10 + c1], p1);
    __syncthreads();
    if (tid < 20) db[(r0 + tid / 10) * 10 + (tid % 10)] = dbl[tid];
}

// ---------------------------------------------------------------------------
// k_sm: bnew = bprev + db/256 ; c = softmax over routes per cap column
__global__ __launch_bounds__(128) void k_sm(const float* __restrict__ bprev,
                                            const float* __restrict__ db,
                                            float* __restrict__ bnew,
                                            float* __restrict__ cij)
{
    __shared__ float red[2];
    __shared__ float red2[2];
    const int c = blockIdx.x;
    const int tid = threadIdx.x;
    float bv[9];
#pragma unroll
    for (int j = 0; j < 9; ++j) {
        const int idx = (tid + j * 128) * 10 + c;
        bv[j] = (bprev ? bprev[idx] : 0.f) + db[idx] * (1.0f / 256.0f);
    }
    float mx = bv[0];
#pragma unroll
    for (int j = 1; j < 9; ++j) mx = fmaxf(mx, bv[j]);
#pragma unroll
    for (int off = 1; off < 64; off <<= 1) mx = fmaxf(mx, __shfl_xor(mx, off, 64));
    if ((tid & 63) == 0) red[tid >> 6] = mx;
    __syncthreads();
    mx = fmaxf(red[0], red[1]);
    float es[9], lsum = 0.f;
#pragma unroll
    for (int j = 0; j < 9; ++j) { es[j] = expf(bv[j] - mx); lsum += es[j]; }
#pragma unroll
    for (int off = 1; off < 64; off <<= 1) lsum += __shfl_xor(lsum, off, 64);
    if ((tid & 63) == 0) red2[tid >> 6] = lsum;
    __syncthreads();
    const float inv = 1.f / (red2[0] + red2[1]);
#pragma unroll
    for (int j = 0; j < 9; ++j) {
        const int idx = (tid + j * 128) * 10 + c;
        bnew[idx] = bv[j];
        cij[idx] = es[j] * inv;
    }
}

// ---------------------------------------------------------------------------
// k_out: blocks 0..255 broadcast c3; blocks 256..271 reduce+squash -> v out
__global__ __launch_bounds__(256) void k_out(const float* __restrict__ s_part,
                                             const float* __restrict__ cij,
                                             float* __restrict__ out, int KB)
{
    const int tid = threadIdx.x;
    if (blockIdx.x < 256) {
        const int b = blockIdx.x;
        float* dst = &out[40960 + (size_t)b * 11520];
        for (int j = tid; j < 11520; j += 256) dst[j] = cij[j];
    } else {
        const int b = (blockIdx.x - 256) * 16 + (tid >> 4);
        const int o = tid & 15;
        for (int c = 0; c < 10; ++c) {
            float s = 0.f;
            const float* p = &s_part[b * 160 + c * 16 + o];
            for (int kbv = 0; kbv < KB; ++kbv) s += p[(size_t)kbv * 40960];
            float sq = s * s;
#pragma unroll
            for (int off = 1; off < 16; off <<= 1) sq += __shfl_xor(sq, off, 16);
            const float scale = (sq / (1.f + sq)) / sqrtf(sq + 1e-9f);
            out[b * 160 + c * 16 + o] = s * scale;
        }
    }
}

// ---------------------------------------------------------------------------
extern "C" void kernel_launch(void* const* d_in, const int* in_sizes, int n_in,
                              void* d_out, int out_size, void* d_ws, size_t ws_size,
                              hipStream_t stream)
{
    const float* x = (const float*)d_in[0];
    const float* W = (const float*)d_in[1];
    float* out = (float*)d_out;
    float* ws  = (float*)d_ws;

    const size_t need64 = (64UL * 40960 + 151040) * sizeof(float);
    const int KB = (ws_size >= need64) ? 64 : 32;

    float* s_part = ws;
    float* b1  = ws + (size_t)KB * 40960;
    float* b2  = b1 + 11520;
    float* c2  = b2 + 11520;
    float* c3  = c2 + 11520;
    float* v1  = c3 + 11520;
    float* v2  = v1 + 40960;
    float* db0 = v2 + 40960;
    float* db1 = db0 + 11520;

    // ---- iteration 1 (c uniform = 1/1152) ----
    k_s<<<16 * KB, 128, 0, stream>>>(x, W, nullptr, s_part, KB);
    k_v<<<80, 256, 0, stream>>>(s_part, v1, KB);
    k_a<<<576, 128, 0, stream>>>(x, v1, W, db0);
    k_sm<<<10, 128, 0, stream>>>(nullptr, db0, b1, c2);

    // ---- iteration 2 ----
    k_s<<<16 * KB, 128, 0, stream>>>(x, W, c2, s_part, KB);
    k_v<<<80, 256, 0, stream>>>(s_part, v2, KB);
    k_a<<<576, 128, 0, stream>>>(x, v2, W, db1);
    k_sm<<<10, 128, 0, stream>>>(b1, db1, b2, c3);

    // ---- iteration 3 + outputs ----
    k_s<<<16 * KB, 128, 0, stream>>>(x, W, c3, s_part, KB);
    k_out<<<272, 256, 0, stream>>>(s_part, c3, out, KB);
}

// Round 3
// 215.055 us; speedup vs baseline: 1.7356x; 1.7356x over previous
//
#include <hip/hip_runtime.h>
#include <math.h>

// Capsule routing, fused, fp32.
// x: [256][1152][8]  W: [1152][10][16][8]
// out: v [256][10][16] (40960) then c_out broadcast [256][1152][10] (2949120)
//
// ws layout (floats):
//   s_part @ 0                KB*40960      (KB = 64 preferred, else 32)
//   part2  @ KB*40960         (KB/8)*40960  (slab partial sums)
//   b1, b2, c2, c3 (11520 each), v1, v2 (40960 each), db0, db1 (11520 each)

// ---------------------------------------------------------------------------
// k_s: s_part[kb][b][n] = sum_{k in slab} x[b][k] * (c[r(k),c(n)] * W[k][n])
// GEMM M=256 N=160 K=9216, split-K. grid = bt(16, M-tile 16) x kb(KB).
// block 128 = tng(32, TN=5) x tmg(4, TM=4). Chunks of 3 routes (24 kk).
__global__ __launch_bounds__(128) void k_s(const float* __restrict__ x,
                                           const float* __restrict__ W,
                                           const float* __restrict__ cw, // [1152][10] or null -> 1/1152
                                           float* __restrict__ s_part,
                                           int KB)
{
    __shared__ float Ws[24 * 160];   // [kk][n]
    __shared__ float Xs[24 * 16];    // [kk][m]
    __shared__ float cwl[368];       // slab's c_ij (Rslab*10 <= 360)

    const int kb = blockIdx.x % KB;
    const int bt = blockIdx.x / KB;
    const int Rslab = 1152 / KB;      // 18 (KB=64) or 36 (KB=32)
    const int nch = Rslab / 3;        // chunks of 3 routes
    const int r_base = kb * Rslab;
    const int b0 = bt * 16;
    const int tid = threadIdx.x;
    const int tng = tid & 31;         // n = tng*5
    const int tmg = tid >> 5;         // m = tmg*4

    const float4* __restrict__ W4 = reinterpret_cast<const float4*>(W);
    const float4* __restrict__ X4 = reinterpret_cast<const float4*>(x);

    const float inv1152 = 1.0f / 1152.0f;
    for (int t = tid; t < Rslab * 10; t += 128)
        cwl[t] = cw ? cw[r_base * 10 + t] : inv1152;

    float acc[4][5];
#pragma unroll
    for (int a = 0; a < 4; ++a)
#pragma unroll
        for (int j = 0; j < 5; ++j) acc[a][j] = 0.f;

    // chunk staging registers (prefetched)
    float4 wreg[8];
    float4 xreg;
    const int xmi = tid / 6;          // 0..21 (valid < 96)
    const int xkq = tid % 6;

    auto load_chunk = [&](int ch) {
        const int r0g = r_base + ch * 3;
#pragma unroll
        for (int q = 0; q < 8; ++q) {
            const int idx = q * 128 + tid;
            if (idx < 960) {
                const int rl = idx / 320, rem = idx % 320;
                wreg[q] = W4[(r0g + rl) * 320 + rem];
            }
        }
        if (tid < 96)
            xreg = X4[(b0 + xmi) * 2304 + r0g * 2 + xkq];
    };
    auto write_chunk = [&](int ch) {
#pragma unroll
        for (int q = 0; q < 8; ++q) {
            const int idx = q * 128 + tid;
            if (idx < 960) {
                const int rl = idx / 320, rem = idx % 320;
                const int h = rem & 1, o = (rem >> 1) & 15, cc = rem >> 5;
                const float sc = cwl[(ch * 3 + rl) * 10 + cc];
                const int kk = rl * 8 + h * 4;
                const int n = cc * 16 + o;
                Ws[(kk + 0) * 160 + n] = wreg[q].x * sc;
                Ws[(kk + 1) * 160 + n] = wreg[q].y * sc;
                Ws[(kk + 2) * 160 + n] = wreg[q].z * sc;
                Ws[(kk + 3) * 160 + n] = wreg[q].w * sc;
            }
        }
        if (tid < 96) {
            Xs[(xkq * 4 + 0) * 16 + xmi] = xreg.x;
            Xs[(xkq * 4 + 1) * 16 + xmi] = xreg.y;
            Xs[(xkq * 4 + 2) * 16 + xmi] = xreg.z;
            Xs[(xkq * 4 + 3) * 16 + xmi] = xreg.w;
        }
    };

    load_chunk(0);
    for (int ch = 0; ch < nch; ++ch) {
        __syncthreads();
        write_chunk(ch);
        __syncthreads();
        if (ch + 1 < nch) load_chunk(ch + 1);   // overlap with compute
#pragma unroll 6
        for (int kk = 0; kk < 24; ++kk) {
            const float4 xv = *reinterpret_cast<const float4*>(&Xs[kk * 16 + tmg * 4]);
            const float* wr = &Ws[kk * 160 + tng * 5];
            const float w0 = wr[0], w1 = wr[1], w2 = wr[2], w3 = wr[3], w4 = wr[4];
            acc[0][0] = fmaf(xv.x, w0, acc[0][0]);
            acc[0][1] = fmaf(xv.x, w1, acc[0][1]);
            acc[0][2] = fmaf(xv.x, w2, acc[0][2]);
            acc[0][3] = fmaf(xv.x, w3, acc[0][3]);
            acc[0][4] = fmaf(xv.x, w4, acc[0][4]);
            acc[1][0] = fmaf(xv.y, w0, acc[1][0]);
            acc[1][1] = fmaf(xv.y, w1, acc[1][1]);
            acc[1][2] = fmaf(xv.y, w2, acc[1][2]);
            acc[1][3] = fmaf(xv.y, w3, acc[1][3]);
            acc[1][4] = fmaf(xv.y, w4, acc[1][4]);
            acc[2][0] = fmaf(xv.z, w0, acc[2][0]);
            acc[2][1] = fmaf(xv.z, w1, acc[2][1]);
            acc[2][2] = fmaf(xv.z, w2, acc[2][2]);
            acc[2][3] = fmaf(xv.z, w3, acc[2][3]);
            acc[2][4] = fmaf(xv.z, w4, acc[2][4]);
            acc[3][0] = fmaf(xv.w, w0, acc[3][0]);
            acc[3][1] = fmaf(xv.w, w1, acc[3][1]);
            acc[3][2] = fmaf(xv.w, w2, acc[3][2]);
            acc[3][3] = fmaf(xv.w, w3, acc[3][3]);
            acc[3][4] = fmaf(xv.w, w4, acc[3][4]);
        }
    }

#pragma unroll
    for (int mi = 0; mi < 4; ++mi) {
        float* dst = &s_part[(size_t)(kb * 256 + b0 + tmg * 4 + mi) * 160 + tng * 5];
#pragma unroll
        for (int j = 0; j < 5; ++j) dst[j] = acc[mi][j];
    }
}

// ---------------------------------------------------------------------------
// k_red: reduce 8 slabs -> 1 partial, float4 coalesced.
// grid = 40 * nsg blocks (nsg = KB/8); block 256. elem4 space = 40960/4 = 10240.
__global__ __launch_bounds__(256) void k_red(const float* __restrict__ s_part,
                                             float* __restrict__ part2, int nsg)
{
    const int eb = blockIdx.x / nsg;
    const int sg = blockIdx.x % nsg;
    const int e4 = eb * 256 + threadIdx.x;
    const float4* __restrict__ sp4 =
        reinterpret_cast<const float4*>(s_part) + (size_t)sg * 8 * 10240 + e4;
    float4 a = sp4[0];
#pragma unroll
    for (int s = 1; s < 8; ++s) {
        const float4 t = sp4[(size_t)s * 10240];
        a.x += t.x; a.y += t.y; a.z += t.z; a.w += t.w;
    }
    reinterpret_cast<float4*>(part2)[(size_t)sg * 10240 + e4] = a;
}

// ---------------------------------------------------------------------------
// k_vfin: sum nsg partials, squash over o (16 consecutive lanes), write v/out.
// grid 160, block 256. e = b*160 + c*16 + o, and (e & 15) == o.
__global__ __launch_bounds__(256) void k_vfin(const float* __restrict__ part2,
                                              float* __restrict__ dst, int nsg)
{
    const int e = blockIdx.x * 256 + threadIdx.x;
    float s = 0.f;
    for (int g = 0; g < nsg; ++g) s += part2[(size_t)g * 40960 + e];
    float sq = s * s;
#pragma unroll
    for (int off = 1; off < 16; off <<= 1) sq += __shfl_xor(sq, off, 16);
    const float scale = (sq / (1.f + sq)) / sqrtf(sq + 1e-9f);
    dst[e] = s * scale;
}

// ---------------------------------------------------------------------------
// k_copy: broadcast cij [11520] -> out[40960 + b*11520], float4, wide grid.
// grid 2880, block 256; 737280 float4 stores total.
__global__ __launch_bounds__(256) void k_copy(const float* __restrict__ cij,
                                              float* __restrict__ out)
{
    const int i = blockIdx.x * 256 + threadIdx.x;
    const float4 v = reinterpret_cast<const float4*>(cij)[i % 2880];
    reinterpret_cast<float4*>(out + 40960)[i] = v;
}

// ---------------------------------------------------------------------------
// k_a: db[r][c] = sum_b sum_o u_hat[b,r,c,o] * v[b,c,o]  (/256 applied in k_sm)
// T-GEMM: T[m=(r,i)][n=(c,o)] = sum_b x[b][m] v[b][n]; M=9216 N=160 K=256.
// grid 576 (M-tile 16 = 2 routes, no K-split). block 128 = tng(32,TN=5) x tmg(4,TM=4).
__global__ __launch_bounds__(128) void k_a(const float* __restrict__ x,
                                           const float* __restrict__ v,
                                           const float* __restrict__ W,
                                           float* __restrict__ db)
{
    __shared__ float Vst[160 * 36];  // [n][b] padded
    __shared__ float Xn[16 * 36];    // [m][b] padded
    __shared__ float dbl[20];
    const int m0 = blockIdx.x * 16;
    const int r0 = m0 >> 3;
    const int tid = threadIdx.x;
    const int tng = tid & 31;
    const int tmg = tid >> 5;
    if (tid < 20) dbl[tid] = 0.f;

    const float4* __restrict__ V4 = reinterpret_cast<const float4*>(v);
    const float4* __restrict__ X4 = reinterpret_cast<const float4*>(x);

    float acc[4][5];
#pragma unroll
    for (int a = 0; a < 4; ++a)
#pragma unroll
        for (int j = 0; j < 5; ++j) acc[a][j] = 0.f;

    const int xbb = tid >> 2, xq = tid & 3;

    for (int bc = 0; bc < 8; ++bc) {
        const int b0 = bc * 32;
        __syncthreads();
        for (int idx = tid; idx < 1280; idx += 128) {
            const int bb = idx / 40, nq = idx % 40;
            const float4 v4 = V4[(b0 + bb) * 40 + nq];
            Vst[(nq * 4 + 0) * 36 + bb] = v4.x;
            Vst[(nq * 4 + 1) * 36 + bb] = v4.y;
            Vst[(nq * 4 + 2) * 36 + bb] = v4.z;
            Vst[(nq * 4 + 3) * 36 + bb] = v4.w;
        }
        {
            const float4 x4 = X4[(b0 + xbb) * 2304 + (m0 >> 2) + xq];
            Xn[(xq * 4 + 0) * 36 + xbb] = x4.x;
            Xn[(xq * 4 + 1) * 36 + xbb] = x4.y;
            Xn[(xq * 4 + 2) * 36 + xbb] = x4.z;
            Xn[(xq * 4 + 3) * 36 + xbb] = x4.w;
        }
        __syncthreads();
#pragma unroll
        for (int s4 = 0; s4 < 8; ++s4) {
            float4 xv[4];
#pragma unroll
            for (int mi = 0; mi < 4; ++mi)
                xv[mi] = *reinterpret_cast<const float4*>(&Xn[(tmg * 4 + mi) * 36 + s4 * 4]);
#pragma unroll
            for (int j = 0; j < 5; ++j) {
                const float4 vj = *reinterpret_cast<const float4*>(&Vst[(tng * 5 + j) * 36 + s4 * 4]);
#pragma unroll
                for (int mi = 0; mi < 4; ++mi) {
                    acc[mi][j] = fmaf(xv[mi].x, vj.x, acc[mi][j]);
                    acc[mi][j] = fmaf(xv[mi].y, vj.y, acc[mi][j]);
                    acc[mi][j] = fmaf(xv[mi].z, vj.z, acc[mi][j]);
                    acc[mi][j] = fmaf(xv[mi].w, vj.w, acc[mi][j]);
                }
            }
        }
    }

    const int rl = tmg >> 1;
    const int c0 = (tng * 5) >> 4;
    const int c1 = (tng * 5 + 4) >> 4;
    float p0 = 0.f, p1 = 0.f;
#pragma unroll
    for (int mi = 0; mi < 4; ++mi) {
        const int ml = tmg * 4 + mi;
        const int i = ml & 7;
        const int r = r0 + rl;
#pragma unroll
        for (int j = 0; j < 5; ++j) {
            const int n = tng * 5 + j;
            const int c = n >> 4, o = n & 15;
            const float w = W[(((r * 10 + c) * 16 + o) * 8) + i];
            const float t = w * acc[mi][j];
            if (c == c0) p0 += t; else p1 += t;
        }
    }
    __syncthreads();
    atomicAdd(&dbl[rl * 10 + c0], p0);
    if (c1 != c0) atomicAdd(&dbl[rl * 10 + c1], p1);
    __syncthreads();
    if (tid < 20) db[(r0 + tid / 10) * 10 + (tid % 10)] = dbl[tid];
}

// ---------------------------------------------------------------------------
// k_sm: bnew = bprev + db/256 ; c = softmax over routes per cap column
__global__ __launch_bounds__(128) void k_sm(const float* __restrict__ bprev,
                                            const float* __restrict__ db,
                                            float* __restrict__ bnew,
                                            float* __restrict__ cij)
{
    __shared__ float red[2];
    __shared__ float red2[2];
    const int c = blockIdx.x;
    const int tid = threadIdx.x;
    float bv[9];
#pragma unroll
    for (int j = 0; j < 9; ++j) {
        const int idx = (tid + j * 128) * 10 + c;
        bv[j] = (bprev ? bprev[idx] : 0.f) + db[idx] * (1.0f / 256.0f);
    }
    float mx = bv[0];
#pragma unroll
    for (int j = 1; j < 9; ++j) mx = fmaxf(mx, bv[j]);
#pragma unroll
    for (int off = 1; off < 64; off <<= 1) mx = fmaxf(mx, __shfl_xor(mx, off, 64));
    if ((tid & 63) == 0) red[tid >> 6] = mx;
    __syncthreads();
    mx = fmaxf(red[0], red[1]);
    float es[9], lsum = 0.f;
#pragma unroll
    for (int j = 0; j < 9; ++j) { es[j] = expf(bv[j] - mx); lsum += es[j]; }
#pragma unroll
    for (int off = 1; off < 64; off <<= 1) lsum += __shfl_xor(lsum, off, 64);
    if ((tid & 63) == 0) red2[tid >> 6] = lsum;
    __syncthreads();
    const float inv = 1.f / (red2[0] + red2[1]);
#pragma unroll
    for (int j = 0; j < 9; ++j) {
        const int idx = (tid + j * 128) * 10 + c;
        bnew[idx] = bv[j];
        cij[idx] = es[j] * inv;
    }
}

// ---------------------------------------------------------------------------
extern "C" void kernel_launch(void* const* d_in, const int* in_sizes, int n_in,
                              void* d_out, int out_size, void* d_ws, size_t ws_size,
                              hipStream_t stream)
{
    const float* x = (const float*)d_in[0];
    const float* W = (const float*)d_in[1];
    float* out = (float*)d_out;
    float* ws  = (float*)d_ws;

    const size_t need64 = (64UL * 40960 + 8UL * 40960 + 151040) * sizeof(float);
    const int KB  = (ws_size >= need64) ? 64 : 32;
    const int nsg = KB / 8;

    float* s_part = ws;
    float* part2  = ws + (size_t)KB * 40960;
    float* b1  = part2 + (size_t)nsg * 40960;
    float* b2  = b1 + 11520;
    float* c2  = b2 + 11520;
    float* c3  = c2 + 11520;
    float* v1  = c3 + 11520;
    float* v2  = v1 + 40960;
    float* db0 = v2 + 40960;
    float* db1 = db0 + 11520;

    // ---- iteration 1 (c uniform = 1/1152) ----
    k_s<<<16 * KB, 128, 0, stream>>>(x, W, nullptr, s_part, KB);
    k_red<<<40 * nsg, 256, 0, stream>>>(s_part, part2, nsg);
    k_vfin<<<160, 256, 0, stream>>>(part2, v1, nsg);
    k_a<<<576, 128, 0, stream>>>(x, v1, W, db0);
    k_sm<<<10, 128, 0, stream>>>(nullptr, db0, b1, c2);

    // ---- iteration 2 ----
    k_s<<<16 * KB, 128, 0, stream>>>(x, W, c2, s_part, KB);
    k_red<<<40 * nsg, 256, 0, stream>>>(s_part, part2, nsg);
    k_vfin<<<160, 256, 0, stream>>>(part2, v2, nsg);
    k_a<<<576, 128, 0, stream>>>(x, v2, W, db1);
    k_sm<<<10, 128, 0, stream>>>(b1, db1, b2, c3);

    // ---- iteration 3 + outputs ----
    k_s<<<16 * KB, 128, 0, stream>>>(x, W, c3, s_part, KB);
    k_red<<<40 * nsg, 256, 0, stream>>>(s_part, part2, nsg);
    k_vfin<<<160, 256, 0, stream>>>(part2, out, nsg);
    k_copy<<<2880, 256, 0, stream>>>(c3, out);
}

// Round 4
// 168.840 us; speedup vs baseline: 2.2107x; 1.2737x over previous
//
#include <hip/hip_runtime.h>
#include <math.h>

// Capsule routing, fused, fp32.
// x: [256][1152][8]  W: [1152][10][16][8]
// out: v [256][10][16] (40960) then c_out broadcast [256][1152][10] (2949120)
//
// ws layout (floats):
//   s_part @ 0                KB*40960      (KB = 64 preferred, else 32)
//   part2  @ KB*40960         (KB/8)*40960  (slab partial sums)
//   b1, b2, c2, c3 (11520 each), v1, v2 (40960 each), db0, db1 (11520 each)

// ---------------------------------------------------------------------------
// k_s: s_part[kb][b][n] = sum_{k in slab} x[b][k] * (c[r(k),c(n)] * W[k][n])
// GEMM M=256 N=160 K=9216, split-K. grid = bt(16, M-tile 16) x kb(KB).
// block 128 = tng(32, TN=5) x tmg(4, TM=4). Chunks of 3 routes (24 kk).
__global__ __launch_bounds__(128) void k_s(const float* __restrict__ x,
                                           const float* __restrict__ W,
                                           const float* __restrict__ cw, // [1152][10] or null -> 1/1152
                                           float* __restrict__ s_part,
                                           int KB)
{
    __shared__ float Ws[24 * 160];   // [kk][n]
    __shared__ float Xs[24 * 16];    // [kk][m]
    __shared__ float cwl[368];       // slab's c_ij (Rslab*10 <= 360)

    const int kb = blockIdx.x % KB;
    const int bt = blockIdx.x / KB;
    const int Rslab = 1152 / KB;      // 18 (KB=64) or 36 (KB=32)
    const int nch = Rslab / 3;        // chunks of 3 routes
    const int r_base = kb * Rslab;
    const int b0 = bt * 16;
    const int tid = threadIdx.x;
    const int tng = tid & 31;         // n = tng*5
    const int tmg = tid >> 5;         // m = tmg*4

    const float4* __restrict__ W4 = reinterpret_cast<const float4*>(W);
    const float4* __restrict__ X4 = reinterpret_cast<const float4*>(x);

    const float inv1152 = 1.0f / 1152.0f;
    for (int t = tid; t < Rslab * 10; t += 128)
        cwl[t] = cw ? cw[r_base * 10 + t] : inv1152;

    float acc[4][5];
#pragma unroll
    for (int a = 0; a < 4; ++a)
#pragma unroll
        for (int j = 0; j < 5; ++j) acc[a][j] = 0.f;

    float4 wreg[8];
    float4 xreg;
    const int xmi = tid / 6;          // 0..21 (valid < 96)
    const int xkq = tid % 6;

    auto load_chunk = [&](int ch) {
        const int r0g = r_base + ch * 3;
#pragma unroll
        for (int q = 0; q < 8; ++q) {
            const int idx = q * 128 + tid;
            if (idx < 960) {
                const int rl = idx / 320, rem = idx % 320;
                wreg[q] = W4[(r0g + rl) * 320 + rem];
            }
        }
        if (tid < 96)
            xreg = X4[(b0 + xmi) * 2304 + r0g * 2 + xkq];
    };
    auto write_chunk = [&](int ch) {
#pragma unroll
        for (int q = 0; q < 8; ++q) {
            const int idx = q * 128 + tid;
            if (idx < 960) {
                const int rl = idx / 320, rem = idx % 320;
                const int h = rem & 1, o = (rem >> 1) & 15, cc = rem >> 5;
                const float sc = cwl[(ch * 3 + rl) * 10 + cc];
                const int kk = rl * 8 + h * 4;
                const int n = cc * 16 + o;
                Ws[(kk + 0) * 160 + n] = wreg[q].x * sc;
                Ws[(kk + 1) * 160 + n] = wreg[q].y * sc;
                Ws[(kk + 2) * 160 + n] = wreg[q].z * sc;
                Ws[(kk + 3) * 160 + n] = wreg[q].w * sc;
            }
        }
        if (tid < 96) {
            Xs[(xkq * 4 + 0) * 16 + xmi] = xreg.x;
            Xs[(xkq * 4 + 1) * 16 + xmi] = xreg.y;
            Xs[(xkq * 4 + 2) * 16 + xmi] = xreg.z;
            Xs[(xkq * 4 + 3) * 16 + xmi] = xreg.w;
        }
    };

    load_chunk(0);
    for (int ch = 0; ch < nch; ++ch) {
        __syncthreads();
        write_chunk(ch);
        __syncthreads();
        if (ch + 1 < nch) load_chunk(ch + 1);   // overlap with compute
#pragma unroll 6
        for (int kk = 0; kk < 24; ++kk) {
            const float4 xv = *reinterpret_cast<const float4*>(&Xs[kk * 16 + tmg * 4]);
            const float* wr = &Ws[kk * 160 + tng * 5];
            const float w0 = wr[0], w1 = wr[1], w2 = wr[2], w3 = wr[3], w4 = wr[4];
            acc[0][0] = fmaf(xv.x, w0, acc[0][0]);
            acc[0][1] = fmaf(xv.x, w1, acc[0][1]);
            acc[0][2] = fmaf(xv.x, w2, acc[0][2]);
            acc[0][3] = fmaf(xv.x, w3, acc[0][3]);
            acc[0][4] = fmaf(xv.x, w4, acc[0][4]);
            acc[1][0] = fmaf(xv.y, w0, acc[1][0]);
            acc[1][1] = fmaf(xv.y, w1, acc[1][1]);
            acc[1][2] = fmaf(xv.y, w2, acc[1][2]);
            acc[1][3] = fmaf(xv.y, w3, acc[1][3]);
            acc[1][4] = fmaf(xv.y, w4, acc[1][4]);
            acc[2][0] = fmaf(xv.z, w0, acc[2][0]);
            acc[2][1] = fmaf(xv.z, w1, acc[2][1]);
            acc[2][2] = fmaf(xv.z, w2, acc[2][2]);
            acc[2][3] = fmaf(xv.z, w3, acc[2][3]);
            acc[2][4] = fmaf(xv.z, w4, acc[2][4]);
            acc[3][0] = fmaf(xv.w, w0, acc[3][0]);
            acc[3][1] = fmaf(xv.w, w1, acc[3][1]);
            acc[3][2] = fmaf(xv.w, w2, acc[3][2]);
            acc[3][3] = fmaf(xv.w, w3, acc[3][3]);
            acc[3][4] = fmaf(xv.w, w4, acc[3][4]);
        }
    }

#pragma unroll
    for (int mi = 0; mi < 4; ++mi) {
        float* dst = &s_part[(size_t)(kb * 256 + b0 + tmg * 4 + mi) * 160 + tng * 5];
#pragma unroll
        for (int j = 0; j < 5; ++j) dst[j] = acc[mi][j];
    }
}

// ---------------------------------------------------------------------------
// k_red: reduce 8 slabs -> 1 partial, float4 coalesced.
__global__ __launch_bounds__(256) void k_red(const float* __restrict__ s_part,
                                             float* __restrict__ part2, int nsg)
{
    const int eb = blockIdx.x / nsg;
    const int sg = blockIdx.x % nsg;
    const int e4 = eb * 256 + threadIdx.x;
    const float4* __restrict__ sp4 =
        reinterpret_cast<const float4*>(s_part) + (size_t)sg * 8 * 10240 + e4;
    float4 a = sp4[0];
#pragma unroll
    for (int s = 1; s < 8; ++s) {
        const float4 t = sp4[(size_t)s * 10240];
        a.x += t.x; a.y += t.y; a.z += t.z; a.w += t.w;
    }
    reinterpret_cast<float4*>(part2)[(size_t)sg * 10240 + e4] = a;
}

// ---------------------------------------------------------------------------
// k_vfin: sum nsg partials, squash over o (16 consecutive lanes), write v/out.
__global__ __launch_bounds__(256) void k_vfin(const float* __restrict__ part2,
                                              float* __restrict__ dst, int nsg)
{
    const int e = blockIdx.x * 256 + threadIdx.x;
    float s = 0.f;
    for (int g = 0; g < nsg; ++g) s += part2[(size_t)g * 40960 + e];
    float sq = s * s;
#pragma unroll
    for (int off = 1; off < 16; off <<= 1) sq += __shfl_xor(sq, off, 16);
    const float scale = (sq / (1.f + sq)) / sqrtf(sq + 1e-9f);
    dst[e] = s * scale;
}

// ---------------------------------------------------------------------------
// k_copy: broadcast cij [11520] -> out[40960 + b*11520], float4, wide grid.
__global__ __launch_bounds__(256) void k_copy(const float* __restrict__ cij,
                                              float* __restrict__ out)
{
    const int i = blockIdx.x * 256 + threadIdx.x;
    const float4 v = reinterpret_cast<const float4*>(cij)[i % 2880];
    reinterpret_cast<float4*>(out + 40960)[i] = v;
}

// ---------------------------------------------------------------------------
// k_a v3: db[r][c] += sum_b sum_o u_hat[b,r,c,o] * v[b,c,o]  (/256 in k_sm)
// T-GEMM: T[m=(r,i)][n=(c,o)] = sum_b x[b][m] v[b][n]; M=9216 N=160 K=256.
// grid 2304 = mb(576, M-tile 16 = 2 routes) x ks(4, batch quarters of 64).
// block 128 = tng(32,TN=5) x tmg(4,TM=4). db accumulated via global atomics.
// LDS layouts conflict-free by construction:
//   Vst[bb][160] : b128 writes at consecutive 16B/lane; scalar reads at
//                  lane-stride 5 floats (gcd(5,32)=1 -> all banks distinct).
//   Xn [bb][16]  : b128 writes consecutive; b128 reads half-wave broadcast.
__global__ __launch_bounds__(128) void k_a(const float* __restrict__ x,
                                           const float* __restrict__ v,
                                           const float* __restrict__ W,
                                           float* __restrict__ db)
{
    __shared__ float Xn[64 * 16];    // [bb][m]
    __shared__ float Vst[32 * 160];  // [bb][n]
    __shared__ float dbl[20];
    const int mb = blockIdx.x >> 2;
    const int ks = blockIdx.x & 3;
    const int m0 = mb * 16;
    const int r0 = m0 >> 3;
    const int b0 = ks * 64;
    const int tid = threadIdx.x;
    const int tng = tid & 31;
    const int tmg = tid >> 5;
    if (tid < 20) dbl[tid] = 0.f;

    const float4* __restrict__ X4 = reinterpret_cast<const float4*>(x);
    const float4* __restrict__ V4 = reinterpret_cast<const float4*>(v);

    // stage x tile [64 bb][16 m]
#pragma unroll
    for (int q = 0; q < 2; ++q) {
        const int idx = q * 128 + tid;
        const int bb = idx >> 2, qq = idx & 3;
        const float4 x4 = X4[(size_t)(b0 + bb) * 2304 + mb * 4 + qq];
        *reinterpret_cast<float4*>(&Xn[bb * 16 + qq * 4]) = x4;
    }

    float acc[4][5];
#pragma unroll
    for (int a = 0; a < 4; ++a)
#pragma unroll
        for (int j = 0; j < 5; ++j) acc[a][j] = 0.f;

    for (int bc = 0; bc < 2; ++bc) {
        __syncthreads();
        // stage Vst [32 bb][160 n]
#pragma unroll
        for (int q = 0; q < 10; ++q) {
            const int idx = q * 128 + tid;
            const int bb = idx / 40, nq = idx % 40;
            *reinterpret_cast<float4*>(&Vst[bb * 160 + nq * 4]) =
                V4[(size_t)(b0 + bc * 32 + bb) * 40 + nq];
        }
        __syncthreads();
#pragma unroll 4
        for (int bb = 0; bb < 32; ++bb) {
            const float4 xv = *reinterpret_cast<const float4*>(
                &Xn[(bc * 32 + bb) * 16 + tmg * 4]);
            const float* vr = &Vst[bb * 160 + tng * 5];
            const float v0 = vr[0], v1 = vr[1], v2 = vr[2], v3 = vr[3], v4_ = vr[4];
            acc[0][0] = fmaf(xv.x, v0, acc[0][0]);
            acc[0][1] = fmaf(xv.x, v1, acc[0][1]);
            acc[0][2] = fmaf(xv.x, v2, acc[0][2]);
            acc[0][3] = fmaf(xv.x, v3, acc[0][3]);
            acc[0][4] = fmaf(xv.x, v4_, acc[0][4]);
            acc[1][0] = fmaf(xv.y, v0, acc[1][0]);
            acc[1][1] = fmaf(xv.y, v1, acc[1][1]);
            acc[1][2] = fmaf(xv.y, v2, acc[1][2]);
            acc[1][3] = fmaf(xv.y, v3, acc[1][3]);
            acc[1][4] = fmaf(xv.y, v4_, acc[1][4]);
            acc[2][0] = fmaf(xv.z, v0, acc[2][0]);
            acc[2][1] = fmaf(xv.z, v1, acc[2][1]);
            acc[2][2] = fmaf(xv.z, v2, acc[2][2]);
            acc[2][3] = fmaf(xv.z, v3, acc[2][3]);
            acc[2][4] = fmaf(xv.z, v4_, acc[2][4]);
            acc[3][0] = fmaf(xv.w, v0, acc[3][0]);
            acc[3][1] = fmaf(xv.w, v1, acc[3][1]);
            acc[3][2] = fmaf(xv.w, v2, acc[3][2]);
            acc[3][3] = fmaf(xv.w, v3, acc[3][3]);
            acc[3][4] = fmaf(xv.w, v4_, acc[3][4]);
        }
    }

    // epilogue: contract T-tile with W -> db partials for this block's 2 routes
    const int rl = tmg >> 1;   // tmg 0,1 -> local route 0; 2,3 -> local route 1
    const int c0 = (tng * 5) >> 4;
    const int c1 = (tng * 5 + 4) >> 4;
    float p0 = 0.f, p1 = 0.f;
#pragma unroll
    for (int mi = 0; mi < 4; ++mi) {
        const int ml = tmg * 4 + mi;
        const int i = ml & 7;
        const int r = r0 + rl;
#pragma unroll
        for (int j = 0; j < 5; ++j) {
            const int n = tng * 5 + j;
            const int c = n >> 4, o = n & 15;
            const float w = W[(((r * 10 + c) * 16 + o) * 8) + i];
            const float t = w * acc[mi][j];
            if (c == c0) p0 += t; else p1 += t;
        }
    }
    __syncthreads();
    atomicAdd(&dbl[rl * 10 + c0], p0);
    if (c1 != c0) atomicAdd(&dbl[rl * 10 + c1], p1);
    __syncthreads();
    if (tid < 20) atomicAdd(&db[(r0 + tid / 10) * 10 + (tid % 10)], dbl[tid]);
}

// ---------------------------------------------------------------------------
// k_sm: bnew = bprev + db/256 ; c = softmax over routes per cap column
__global__ __launch_bounds__(128) void k_sm(const float* __restrict__ bprev,
                                            const float* __restrict__ db,
                                            float* __restrict__ bnew,
                                            float* __restrict__ cij)
{
    __shared__ float red[2];
    __shared__ float red2[2];
    const int c = blockIdx.x;
    const int tid = threadIdx.x;
    float bv[9];
#pragma unroll
    for (int j = 0; j < 9; ++j) {
        const int idx = (tid + j * 128) * 10 + c;
        bv[j] = (bprev ? bprev[idx] : 0.f) + db[idx] * (1.0f / 256.0f);
    }
    float mx = bv[0];
#pragma unroll
    for (int j = 1; j < 9; ++j) mx = fmaxf(mx, bv[j]);
#pragma unroll
    for (int off = 1; off < 64; off <<= 1) mx = fmaxf(mx, __shfl_xor(mx, off, 64));
    if ((tid & 63) == 0) red[tid >> 6] = mx;
    __syncthreads();
    mx = fmaxf(red[0], red[1]);
    float es[9], lsum = 0.f;
#pragma unroll
    for (int j = 0; j < 9; ++j) { es[j] = expf(bv[j] - mx); lsum += es[j]; }
#pragma unroll
    for (int off = 1; off < 64; off <<= 1) lsum += __shfl_xor(lsum, off, 64);
    if ((tid & 63) == 0) red2[tid >> 6] = lsum;
    __syncthreads();
    const float inv = 1.f / (red2[0] + red2[1]);
#pragma unroll
    for (int j = 0; j < 9; ++j) {
        const int idx = (tid + j * 128) * 10 + c;
        bnew[idx] = bv[j];
        cij[idx] = es[j] * inv;
    }
}

// ---------------------------------------------------------------------------
extern "C" void kernel_launch(void* const* d_in, const int* in_sizes, int n_in,
                              void* d_out, int out_size, void* d_ws, size_t ws_size,
                              hipStream_t stream)
{
    const float* x = (const float*)d_in[0];
    const float* W = (const float*)d_in[1];
    float* out = (float*)d_out;
    float* ws  = (float*)d_ws;

    const size_t need64 = (64UL * 40960 + 8UL * 40960 + 151040) * sizeof(float);
    const int KB  = (ws_size >= need64) ? 64 : 32;
    const int nsg = KB / 8;

    float* s_part = ws;
    float* part2  = ws + (size_t)KB * 40960;
    float* b1  = part2 + (size_t)nsg * 40960;
    float* b2  = b1 + 11520;
    float* c2  = b2 + 11520;
    float* c3  = c2 + 11520;
    float* v1  = c3 + 11520;
    float* v2  = v1 + 40960;
    float* db0 = v2 + 40960;
    float* db1 = db0 + 11520;

    // zero both db atomic accumulators (contiguous)
    hipMemsetAsync(db0, 0, 2 * 11520 * sizeof(float), stream);

    // ---- iteration 1 (c uniform = 1/1152) ----
    k_s<<<16 * KB, 128, 0, stream>>>(x, W, nullptr, s_part, KB);
    k_red<<<40 * nsg, 256, 0, stream>>>(s_part, part2, nsg);
    k_vfin<<<160, 256, 0, stream>>>(part2, v1, nsg);
    k_a<<<2304, 128, 0, stream>>>(x, v1, W, db0);
    k_sm<<<10, 128, 0, stream>>>(nullptr, db0, b1, c2);

    // ---- iteration 2 ----
    k_s<<<16 * KB, 128, 0, stream>>>(x, W, c2, s_part, KB);
    k_red<<<40 * nsg, 256, 0, stream>>>(s_part, part2, nsg);
    k_vfin<<<160, 256, 0, stream>>>(part2, v2, nsg);
    k_a<<<2304, 128, 0, stream>>>(x, v2, W, db1);
    k_sm<<<10, 128, 0, stream>>>(b1, db1, b2, c3);

    // ---- iteration 3 + outputs ----
    k_s<<<16 * KB, 128, 0, stream>>>(x, W, c3, s_part, KB);
    k_red<<<40 * nsg, 256, 0, stream>>>(s_part, part2, nsg);
    k_vfin<<<160, 256, 0, stream>>>(part2, out, nsg);
    k_copy<<<2880, 256, 0, stream>>>(c3, out);
}